// Round 1
// baseline (3030.955 us; speedup 1.0000x reference)
//
#include <hip/hip_runtime.h>
#include <math.h>

#define NB 256    // batch
#define NH 256    // hidden
#define NE 128    // embed
#define NV 32000  // vocab
#define TT 16     // timesteps
#define NZ 64     // noise dim

// ---------- helpers ----------
__device__ __forceinline__ unsigned fkey(float f) {
    // monotone float -> uint mapping (orderable)
    unsigned u = __float_as_uint(f);
    return (u & 0x80000000u) ? ~u : (u | 0x80000000u);
}

__device__ __forceinline__ unsigned long long sx64(unsigned long long v, int m) {
    unsigned lo = (unsigned)__shfl_xor((int)(unsigned)(v & 0xffffffffull), m, 64);
    unsigned hi = (unsigned)__shfl_xor((int)(unsigned)(v >> 32), m, 64);
    return ((unsigned long long)hi << 32) | (unsigned long long)lo;
}

__device__ __forceinline__ int unpack_idx(unsigned long long key) {
    return (int)(NV - 1 - (unsigned)(key & 0xffffffffull));
}

// ---------- zero the 512MB output ----------
__global__ void k_zero(float4* __restrict__ p, int n4) {
    int i = blockIdx.x * blockDim.x + threadIdx.x;
    int stride = gridDim.x * blockDim.x;
    float4 z = make_float4(0.f, 0.f, 0.f, 0.f);
    for (; i < n4; i += stride) p[i] = z;
}

// ---------- h0 = tanh(noise @ fcW^T + fcb); c = 0; packed = 0 ----------
__global__ void k_init(const float* __restrict__ noise, const float* __restrict__ fcW,
                       const float* __restrict__ fcb, float* __restrict__ h,
                       float* __restrict__ c, unsigned long long* __restrict__ packed) {
    __shared__ float ns[NZ];
    int b = blockIdx.x, tid = threadIdx.x;
    if (tid < NZ) ns[tid] = noise[b * NZ + tid];
    __syncthreads();
    float acc = fcb[tid];
    const float* w = &fcW[(size_t)tid * NZ];
#pragma unroll
    for (int k = 0; k < NZ; k++) acc += ns[k] * w[k];
    h[b * NH + tid] = tanhf(acc);
    c[b * NH + tid] = 0.f;
    if (tid < TT) packed[tid * NB + b] = 0ull;
}

// ---------- gates = [x | h] @ [Wih | Whh]^T + bih + bhh ----------
// M=256 (b), N=1024 (gate rows), K=384.  x is embed_W[idx_prev[b]] (indirect).
// Tile 64x64, Ktile 16, 256 threads, 4x4 microtile.
__global__ __launch_bounds__(256) void k_gates(
    const float* __restrict__ h, const float* __restrict__ embW,
    const float* __restrict__ Wih, const float* __restrict__ Whh,
    const float* __restrict__ bih, const float* __restrict__ bhh,
    float* __restrict__ gates, const unsigned long long* __restrict__ packedPrev, int t) {
    __shared__ float As[16][68];
    __shared__ float Ws[16][68];
    __shared__ int idxs[64];
    int tid = threadIdx.x;
    int n0 = blockIdx.x * 64, m0 = blockIdx.y * 64;
    if (tid < 64) {
        idxs[tid] = (t == 0) ? 0 : unpack_idx(packedPrev[m0 + tid]);
    }
    float acc[4][4] = {};
    int row = tid >> 2, kq = tid & 3;
    int ty = tid >> 4, tx = tid & 15;
    for (int kc = 0; kc < 24; kc++) {
        __syncthreads();
        int kg = kc * 16 + kq * 4;
        float4 a4, w4;
        if (kg < NE) {
            a4 = *(const float4*)&embW[(size_t)idxs[row] * NE + kg];
            w4 = *(const float4*)&Wih[(size_t)(n0 + row) * NE + kg];
        } else {
            a4 = *(const float4*)&h[(size_t)(m0 + row) * NH + kg - NE];
            w4 = *(const float4*)&Whh[(size_t)(n0 + row) * NH + kg - NE];
        }
        As[kq * 4 + 0][row] = a4.x; As[kq * 4 + 1][row] = a4.y;
        As[kq * 4 + 2][row] = a4.z; As[kq * 4 + 3][row] = a4.w;
        Ws[kq * 4 + 0][row] = w4.x; Ws[kq * 4 + 1][row] = w4.y;
        Ws[kq * 4 + 2][row] = w4.z; Ws[kq * 4 + 3][row] = w4.w;
        __syncthreads();
#pragma unroll
        for (int kk = 0; kk < 16; kk++) {
            float a[4], w[4];
            *(float4*)&a[0] = *(const float4*)&As[kk][ty * 4];
            *(float4*)&w[0] = *(const float4*)&Ws[kk][tx * 4];
#pragma unroll
            for (int i = 0; i < 4; i++)
#pragma unroll
                for (int j = 0; j < 4; j++) acc[i][j] += a[i] * w[j];
        }
    }
#pragma unroll
    for (int i = 0; i < 4; i++) {
        int b = m0 + ty * 4 + i;
#pragma unroll
        for (int j = 0; j < 4; j++) {
            int n = n0 + tx * 4 + j;
            gates[(size_t)b * (4 * NH) + n] = acc[i][j] + bih[n] + bhh[n];
        }
    }
}

// ---------- LSTM cell pointwise + one-hot write for step t-1 ----------
__global__ void k_cell(const float* __restrict__ gates, float* __restrict__ c,
                       float* __restrict__ h, const unsigned long long* __restrict__ packed,
                       float* __restrict__ out, int t) {
    int b = blockIdx.x, j = threadIdx.x;
    const float* g = &gates[(size_t)b * (4 * NH)];
    float ig = g[j], fg = g[NH + j], gg = g[2 * NH + j], og = g[3 * NH + j];
    float is = 1.f / (1.f + expf(-ig));
    float fs = 1.f / (1.f + expf(-fg));
    float gt = tanhf(gg);
    float os = 1.f / (1.f + expf(-og));
    float cn = fs * c[b * NH + j] + is * gt;
    c[b * NH + j] = cn;
    h[b * NH + j] = os * tanhf(cn);
    if (t > 0 && j == 0) {
        int idx = unpack_idx(packed[(size_t)(t - 1) * NB + b]);
        out[((size_t)b * TT + (t - 1)) * NV + idx] = 1.0f;
    }
}

// ---------- logits + gumbel + argmax ----------
// M=256 (b), N=32000 (v), K=256. Tile 128x128, Ktile 16, 256 threads, 8x8 micro.
__global__ __launch_bounds__(256) void k_logits(
    const float* __restrict__ h, const float* __restrict__ outW,
    const float* __restrict__ outb, const float* __restrict__ gu,   // + t*NB*NV
    unsigned long long* __restrict__ packedT) {                     // + t*NB
    __shared__ float As[16][132];
    __shared__ float Bs[16][132];
    int tid = threadIdx.x;
    int v0 = blockIdx.x * 128, m0 = blockIdx.y * 128;
    float acc[8][8] = {};
    int ty = tid >> 4, tx = tid & 15;
    for (int kc = 0; kc < 16; kc++) {
        __syncthreads();
#pragma unroll
        for (int s = 0; s < 2; s++) {
            int slot = tid + s * 256;
            int row = slot >> 2, kq = slot & 3;
            int kg = kc * 16 + kq * 4;
            float4 a = *(const float4*)&h[(size_t)(m0 + row) * NH + kg];
            float4 w = *(const float4*)&outW[(size_t)(v0 + row) * NH + kg];
            As[kq * 4 + 0][row] = a.x; As[kq * 4 + 1][row] = a.y;
            As[kq * 4 + 2][row] = a.z; As[kq * 4 + 3][row] = a.w;
            Bs[kq * 4 + 0][row] = w.x; Bs[kq * 4 + 1][row] = w.y;
            Bs[kq * 4 + 2][row] = w.z; Bs[kq * 4 + 3][row] = w.w;
        }
        __syncthreads();
#pragma unroll
        for (int kk = 0; kk < 16; kk++) {
            float a[8], bb[8];
            *(float4*)&a[0] = *(const float4*)&As[kk][ty * 8];
            *(float4*)&a[4] = *(const float4*)&As[kk][ty * 8 + 4];
            *(float4*)&bb[0] = *(const float4*)&Bs[kk][tx * 8];
            *(float4*)&bb[4] = *(const float4*)&Bs[kk][tx * 8 + 4];
#pragma unroll
            for (int i = 0; i < 8; i++)
#pragma unroll
                for (int j = 0; j < 8; j++) acc[i][j] += a[i] * bb[j];
        }
    }
    // epilogue: + out_b + gumbel, per-row argmax
    int vb = v0 + tx * 8;
    float ob[8];
    *(float4*)&ob[0] = *(const float4*)&outb[vb];
    *(float4*)&ob[4] = *(const float4*)&outb[vb + 4];
#pragma unroll
    for (int i = 0; i < 8; i++) {
        int b = m0 + ty * 8 + i;
        float uu[8];
        const float* up = &gu[(size_t)b * NV + vb];
        *(float4*)&uu[0] = *(const float4*)up;
        *(float4*)&uu[4] = *(const float4*)(up + 4);
        float best = -1e30f;
        int bidx = vb;
#pragma unroll
        for (int j = 0; j < 8; j++) {
            float gmb = -logf(-logf(uu[j] + 1e-10f) + 1e-10f);
            float val = acc[i][j] + ob[j] + gmb;
            if (val > best) { best = val; bidx = vb + j; }  // '>' keeps first on tie
        }
        unsigned long long key =
            ((unsigned long long)fkey(best) << 32) | (unsigned)(NV - 1 - bidx);
#pragma unroll
        for (int m = 1; m <= 8; m <<= 1) {
            unsigned long long o = sx64(key, m);
            if (o > key) key = o;
        }
        if (tx == 0) atomicMax(&packedT[b], key);
    }
}

// ---------- final one-hot for t = T-1 ----------
__global__ void k_final(const unsigned long long* __restrict__ packed, float* __restrict__ out) {
    int b = threadIdx.x;
    int idx = unpack_idx(packed[(size_t)(TT - 1) * NB + b]);
    out[((size_t)b * TT + (TT - 1)) * NV + idx] = 1.0f;
}

extern "C" void kernel_launch(void* const* d_in, const int* in_sizes, int n_in,
                              void* d_out, int out_size, void* d_ws, size_t ws_size,
                              hipStream_t stream) {
    const float* noise = (const float*)d_in[0];
    const float* gu    = (const float*)d_in[1];
    const float* fcW   = (const float*)d_in[2];
    const float* fcb   = (const float*)d_in[3];
    const float* embW  = (const float*)d_in[4];
    const float* Wih   = (const float*)d_in[5];
    const float* Whh   = (const float*)d_in[6];
    const float* bih   = (const float*)d_in[7];
    const float* bhh   = (const float*)d_in[8];
    const float* outW  = (const float*)d_in[9];
    const float* outb  = (const float*)d_in[10];
    float* out = (float*)d_out;

    float* ws = (float*)d_ws;
    float* h     = ws;                    // [NB*NH]
    float* c     = ws + NB * NH;          // [NB*NH]
    float* gates = ws + 2 * NB * NH;      // [NB*4*NH]
    unsigned long long* packed =
        (unsigned long long*)(ws + 2 * NB * NH + NB * 4 * NH);  // [TT*NB]

    int n4 = (NB * TT * NV) / 4;
    k_zero<<<4096, 256, 0, stream>>>((float4*)out, n4);
    k_init<<<NB, NH, 0, stream>>>(noise, fcW, fcb, h, c, packed);

    for (int t = 0; t < TT; t++) {
        const unsigned long long* pprev = (t == 0) ? packed : packed + (size_t)(t - 1) * NB;
        k_gates<<<dim3(16, 4), 256, 0, stream>>>(h, embW, Wih, Whh, bih, bhh, gates, pprev, t);
        k_cell<<<NB, NH, 0, stream>>>(gates, c, h, packed, out, t);
        k_logits<<<dim3(NV / 128, 2), 256, 0, stream>>>(
            h, outW, outb, gu + (size_t)t * NB * NV, packed + (size_t)t * NB);
    }
    k_final<<<1, NB, 0, stream>>>(packed, out);
}

// Round 2
// 2993.198 us; speedup vs baseline: 1.0126x; 1.0126x over previous
//
#include <hip/hip_runtime.h>
#include <math.h>

#define NB 256    // batch
#define NH 256    // hidden
#define NE 128    // embed
#define NV 32000  // vocab
#define TT 16     // timesteps
#define NZ 64     // noise dim

typedef __attribute__((ext_vector_type(8))) short short8;
typedef __attribute__((ext_vector_type(16))) float f32x16;

// ---------- helpers ----------
__device__ __forceinline__ unsigned fkey(float f) {
    unsigned u = __float_as_uint(f);
    return (u & 0x80000000u) ? ~u : (u | 0x80000000u);
}

__device__ __forceinline__ unsigned long long sx64(unsigned long long v, int m) {
    unsigned lo = (unsigned)__shfl_xor((int)(unsigned)(v & 0xffffffffull), m, 64);
    unsigned hi = (unsigned)__shfl_xor((int)(unsigned)(v >> 32), m, 64);
    return ((unsigned long long)hi << 32) | (unsigned long long)lo;
}

__device__ __forceinline__ int unpack_idx(unsigned long long key) {
    return (int)(NV - 1 - (unsigned)(key & 0xffffffffull));
}

__device__ __forceinline__ unsigned short bf16_rne(float f) {
    unsigned u = __float_as_uint(f);
    unsigned r = u + 0x7FFFu + ((u >> 16) & 1u);
    return (unsigned short)(r >> 16);
}
__device__ __forceinline__ float bf16_f(unsigned short h) {
    return __uint_as_float(((unsigned)h) << 16);
}
__device__ __forceinline__ void split3(float x, unsigned short& a, unsigned short& b,
                                       unsigned short& c) {
    a = bf16_rne(x);
    float r = x - bf16_f(a);
    b = bf16_rne(r);
    r -= bf16_f(b);
    c = bf16_rne(r);
}

// ---------- zero the 512MB output ----------
__global__ void k_zero(float4* __restrict__ p, int n4) {
    int i = blockIdx.x * blockDim.x + threadIdx.x;
    int stride = gridDim.x * blockDim.x;
    float4 z = make_float4(0.f, 0.f, 0.f, 0.f);
    for (; i < n4; i += stride) p[i] = z;
}

// ---------- split out_W -> 3 bf16 planes (once per launch) ----------
__global__ void k_convW(const float* __restrict__ W, unsigned short* __restrict__ W1,
                        unsigned short* __restrict__ W2, unsigned short* __restrict__ W3,
                        int n4) {
    int i = blockIdx.x * blockDim.x + threadIdx.x;
    int stride = gridDim.x * blockDim.x;
    for (; i < n4; i += stride) {
        float4 v = ((const float4*)W)[i];
        ushort4 a, b, c;
        split3(v.x, a.x, b.x, c.x);
        split3(v.y, a.y, b.y, c.y);
        split3(v.z, a.z, b.z, c.z);
        split3(v.w, a.w, b.w, c.w);
        ((ushort4*)W1)[i] = a;
        ((ushort4*)W2)[i] = b;
        ((ushort4*)W3)[i] = c;
    }
}

// ---------- h0 = tanh(noise @ fcW^T + fcb); c = 0; packed = 0; h splits ----------
__global__ void k_init(const float* __restrict__ noise, const float* __restrict__ fcW,
                       const float* __restrict__ fcb, float* __restrict__ h,
                       float* __restrict__ c, unsigned long long* __restrict__ packed,
                       unsigned short* __restrict__ h1, unsigned short* __restrict__ h2,
                       unsigned short* __restrict__ h3) {
    __shared__ float ns[NZ];
    int b = blockIdx.x, tid = threadIdx.x;
    if (tid < NZ) ns[tid] = noise[b * NZ + tid];
    __syncthreads();
    float acc = fcb[tid];
    const float* w = &fcW[(size_t)tid * NZ];
#pragma unroll
    for (int k = 0; k < NZ; k++) acc += ns[k] * w[k];
    float hv = tanhf(acc);
    h[b * NH + tid] = hv;
    c[b * NH + tid] = 0.f;
    split3(hv, h1[b * NH + tid], h2[b * NH + tid], h3[b * NH + tid]);
    if (tid < TT) packed[tid * NB + b] = 0ull;
}

// ---------- gates = [x | h] @ [Wih | Whh]^T + bih + bhh (fp32) ----------
__global__ __launch_bounds__(256) void k_gates(
    const float* __restrict__ h, const float* __restrict__ embW,
    const float* __restrict__ Wih, const float* __restrict__ Whh,
    const float* __restrict__ bih, const float* __restrict__ bhh,
    float* __restrict__ gates, const unsigned long long* __restrict__ packedPrev, int t) {
    __shared__ float As[16][68];
    __shared__ float Ws[16][68];
    __shared__ int idxs[64];
    int tid = threadIdx.x;
    int n0 = blockIdx.x * 64, m0 = blockIdx.y * 64;
    if (tid < 64) {
        idxs[tid] = (t == 0) ? 0 : unpack_idx(packedPrev[m0 + tid]);
    }
    float acc[4][4] = {};
    int row = tid >> 2, kq = tid & 3;
    int ty = tid >> 4, tx = tid & 15;
    for (int kc = 0; kc < 24; kc++) {
        __syncthreads();
        int kg = kc * 16 + kq * 4;
        float4 a4, w4;
        if (kg < NE) {
            a4 = *(const float4*)&embW[(size_t)idxs[row] * NE + kg];
            w4 = *(const float4*)&Wih[(size_t)(n0 + row) * NE + kg];
        } else {
            a4 = *(const float4*)&h[(size_t)(m0 + row) * NH + kg - NE];
            w4 = *(const float4*)&Whh[(size_t)(n0 + row) * NH + kg - NE];
        }
        As[kq * 4 + 0][row] = a4.x; As[kq * 4 + 1][row] = a4.y;
        As[kq * 4 + 2][row] = a4.z; As[kq * 4 + 3][row] = a4.w;
        Ws[kq * 4 + 0][row] = w4.x; Ws[kq * 4 + 1][row] = w4.y;
        Ws[kq * 4 + 2][row] = w4.z; Ws[kq * 4 + 3][row] = w4.w;
        __syncthreads();
#pragma unroll
        for (int kk = 0; kk < 16; kk++) {
            float a[4], w[4];
            *(float4*)&a[0] = *(const float4*)&As[kk][ty * 4];
            *(float4*)&w[0] = *(const float4*)&Ws[kk][tx * 4];
#pragma unroll
            for (int i = 0; i < 4; i++)
#pragma unroll
                for (int j = 0; j < 4; j++) acc[i][j] += a[i] * w[j];
        }
    }
#pragma unroll
    for (int i = 0; i < 4; i++) {
        int b = m0 + ty * 4 + i;
#pragma unroll
        for (int j = 0; j < 4; j++) {
            int n = n0 + tx * 4 + j;
            gates[(size_t)b * (4 * NH) + n] = acc[i][j] + bih[n] + bhh[n];
        }
    }
}

// ---------- LSTM cell pointwise + h splits + one-hot write for step t-1 ----------
__global__ void k_cell(const float* __restrict__ gates, float* __restrict__ c,
                       float* __restrict__ h, const unsigned long long* __restrict__ packed,
                       float* __restrict__ out, int t, unsigned short* __restrict__ h1,
                       unsigned short* __restrict__ h2, unsigned short* __restrict__ h3) {
    int b = blockIdx.x, j = threadIdx.x;
    const float* g = &gates[(size_t)b * (4 * NH)];
    float ig = g[j], fg = g[NH + j], gg = g[2 * NH + j], og = g[3 * NH + j];
    float is = 1.f / (1.f + expf(-ig));
    float fs = 1.f / (1.f + expf(-fg));
    float gt = tanhf(gg);
    float os = 1.f / (1.f + expf(-og));
    float cn = fs * c[b * NH + j] + is * gt;
    c[b * NH + j] = cn;
    float hv = os * tanhf(cn);
    h[b * NH + j] = hv;
    split3(hv, h1[b * NH + j], h2[b * NH + j], h3[b * NH + j]);
    if (t > 0 && j == 0) {
        int idx = unpack_idx(packed[(size_t)(t - 1) * NB + b]);
        out[((size_t)b * TT + (t - 1)) * NV + idx] = 1.0f;
    }
}

// ---------- logits via 3-term bf16-split MFMA + gumbel + argmax ----------
// C[b][v] = sum_k h[b][k] W[v][k].  M=256 (all), N=64/block, K=256.
// Wave tile 64x64 as 2x2 of 32x32x16 mfma; 6 split products (~fp32 accuracy).
// LDS in fragment-chunk order: staging reads are 64B/row coalesced, frag reads
// are conflict-free ds_read_b128.
__global__ __launch_bounds__(256, 2) void k_logits(
    const unsigned short* __restrict__ h1, const unsigned short* __restrict__ h2,
    const unsigned short* __restrict__ h3, const unsigned short* __restrict__ W1,
    const unsigned short* __restrict__ W2, const unsigned short* __restrict__ W3,
    const float* __restrict__ outb, const float* __restrict__ gu,
    unsigned long long* __restrict__ packedT) {
    // A: [s][rowgrp 8][q 4][lane 32] chunks of 8 bf16 = 24576 ushorts (48 KB)
    // B: [s][ngrp 2][q 4][lane 32]                     =  6144 ushorts (12 KB)
    __shared__ unsigned short lds[30720];
    const int tid = threadIdx.x;
    const int v0 = blockIdx.x * 64;
    const int lane = tid & 63;
    const int w = tid >> 6;  // wave: rows w*64..w*64+63
    const int l31 = lane & 31;
    const int half = lane >> 5;

    const unsigned short* hs[3] = {h1, h2, h3};
    const unsigned short* Wsp[3] = {W1, W2, W3};

    f32x16 acc[2][2] = {};

    for (int kc = 0; kc < 8; kc++) {
        __syncthreads();
        int kg = kc * 32;
        // stage A: 3 x 256 rows x 32 k  (3072 16B-chunks, 12/thread)
#pragma unroll
        for (int s = 0; s < 3; s++) {
#pragma unroll
            for (int j = 0; j < 4; j++) {
                int rem = tid + j * 256;      // 0..1023
                int row = rem >> 2;           // 0..255
                int q = rem & 3;              // 64B row slice -> 4 chunks
                short8 v = *(const short8*)&hs[s][(size_t)row * NH + kg + q * 8];
                *(short8*)&lds[(((s * 8 + (row >> 5)) * 4 + q) << 8) + ((row & 31) << 3)] = v;
            }
        }
        // stage B: 3 x 64 rows x 32 k (768 chunks, 3/thread)
#pragma unroll
        for (int s = 0; s < 3; s++) {
            int n = tid >> 2, q = tid & 3;
            short8 v = *(const short8*)&Wsp[s][(size_t)(v0 + n) * NH + kg + q * 8];
            *(short8*)&lds[24576 + (((s * 2 + (n >> 5)) * 4 + q) << 8) + ((n & 31) << 3)] = v;
        }
        __syncthreads();
#pragma unroll
        for (int ks = 0; ks < 2; ks++) {
            int q = ks * 2 + half;
            short8 af[3][2], bf[3][2];
#pragma unroll
            for (int s = 0; s < 3; s++) {
#pragma unroll
                for (int mt = 0; mt < 2; mt++)
                    af[s][mt] = *(const short8*)&lds[(((s * 8 + (w * 2 + mt)) * 4 + q) << 8) + (l31 << 3)];
#pragma unroll
                for (int nt = 0; nt < 2; nt++)
                    bf[s][nt] = *(const short8*)&lds[24576 + (((s * 2 + nt) * 4 + q) << 8) + (l31 << 3)];
            }
#pragma unroll
            for (int mt = 0; mt < 2; mt++)
#pragma unroll
                for (int nt = 0; nt < 2; nt++) {
                    f32x16 a = acc[mt][nt];
                    a = __builtin_amdgcn_mfma_f32_32x32x16_bf16(af[0][mt], bf[0][nt], a, 0, 0, 0);
                    a = __builtin_amdgcn_mfma_f32_32x32x16_bf16(af[0][mt], bf[1][nt], a, 0, 0, 0);
                    a = __builtin_amdgcn_mfma_f32_32x32x16_bf16(af[1][mt], bf[0][nt], a, 0, 0, 0);
                    a = __builtin_amdgcn_mfma_f32_32x32x16_bf16(af[1][mt], bf[1][nt], a, 0, 0, 0);
                    a = __builtin_amdgcn_mfma_f32_32x32x16_bf16(af[0][mt], bf[2][nt], a, 0, 0, 0);
                    a = __builtin_amdgcn_mfma_f32_32x32x16_bf16(af[2][mt], bf[0][nt], a, 0, 0, 0);
                    acc[mt][nt] = a;
                }
        }
    }

    // epilogue: + out_b + gumbel, per-row argmax.
    // C layout (32x32): col = l31, row = (reg&3) + 8*(reg>>2) + 4*half
    int cn0 = v0 + l31;
    int cn1 = v0 + 32 + l31;
    float ob0 = outb[cn0], ob1 = outb[cn1];
#pragma unroll
    for (int mt = 0; mt < 2; mt++) {
#pragma unroll
        for (int r = 0; r < 16; r++) {
            int row = w * 64 + mt * 32 + (r & 3) + 8 * (r >> 2) + 4 * half;
            float u0 = gu[(size_t)row * NV + cn0];
            float u1 = gu[(size_t)row * NV + cn1];
            float gm0 = -logf(-logf(u0 + 1e-10f) + 1e-10f);
            float gm1 = -logf(-logf(u1 + 1e-10f) + 1e-10f);
            float val0 = acc[mt][0][r] + ob0 + gm0;
            float val1 = acc[mt][1][r] + ob1 + gm1;
            float best = val0;
            int bidx = cn0;
            if (val1 > val0) { best = val1; bidx = cn1; }  // tie -> smaller idx
            unsigned long long key =
                ((unsigned long long)fkey(best) << 32) | (unsigned)(NV - 1 - bidx);
#pragma unroll
            for (int m = 1; m <= 16; m <<= 1) {
                unsigned long long o = sx64(key, m);
                if (o > key) key = o;
            }
            if (l31 == 0) atomicMax(&packedT[row], key);
        }
    }
}

// ---------- final one-hot for t = T-1 ----------
__global__ void k_final(const unsigned long long* __restrict__ packed, float* __restrict__ out) {
    int b = threadIdx.x;
    int idx = unpack_idx(packed[(size_t)(TT - 1) * NB + b]);
    out[((size_t)b * TT + (TT - 1)) * NV + idx] = 1.0f;
}

extern "C" void kernel_launch(void* const* d_in, const int* in_sizes, int n_in,
                              void* d_out, int out_size, void* d_ws, size_t ws_size,
                              hipStream_t stream) {
    const float* noise = (const float*)d_in[0];
    const float* gu    = (const float*)d_in[1];
    const float* fcW   = (const float*)d_in[2];
    const float* fcb   = (const float*)d_in[3];
    const float* embW  = (const float*)d_in[4];
    const float* Wih   = (const float*)d_in[5];
    const float* Whh   = (const float*)d_in[6];
    const float* bih   = (const float*)d_in[7];
    const float* bhh   = (const float*)d_in[8];
    const float* outW  = (const float*)d_in[9];
    const float* outb  = (const float*)d_in[10];
    float* out = (float*)d_out;

    float* ws = (float*)d_ws;
    float* h     = ws;                 // 65536 f
    float* c     = ws + 65536;         // 65536 f
    float* gates = ws + 131072;        // 262144 f
    unsigned long long* packed = (unsigned long long*)(ws + 393216);  // 4096 u64 (8192 f)
    unsigned short* h1 = (unsigned short*)(ws + 401408);  // 65536 us (32768 f each)
    unsigned short* h2 = (unsigned short*)(ws + 434176);
    unsigned short* h3 = (unsigned short*)(ws + 466944);
    unsigned short* W1 = (unsigned short*)(ws + 499712);  // 8192000 us (4096000 f each)
    unsigned short* W2 = (unsigned short*)(ws + 4595712);
    unsigned short* W3 = (unsigned short*)(ws + 8691712);

    int n4 = (NB * TT * NV) / 4;
    k_zero<<<8192, 256, 0, stream>>>((float4*)out, n4);
    k_convW<<<2048, 256, 0, stream>>>(outW, W1, W2, W3, (NV * NH) / 4);
    k_init<<<NB, NH, 0, stream>>>(noise, fcW, fcb, h, c, packed, h1, h2, h3);

    for (int t = 0; t < TT; t++) {
        const unsigned long long* pprev = (t == 0) ? packed : packed + (size_t)(t - 1) * NB;
        k_gates<<<dim3(16, 4), 256, 0, stream>>>(h, embW, Wih, Whh, bih, bhh, gates, pprev, t);
        k_cell<<<NB, NH, 0, stream>>>(gates, c, h, packed, out, t, h1, h2, h3);
        k_logits<<<NV / 64, 256, 0, stream>>>(h1, h2, h3, W1, W2, W3, outb,
                                              gu + (size_t)t * NB * NV,
                                              packed + (size_t)t * NB);
    }
    k_final<<<1, NB, 0, stream>>>(packed, out);
}